// Round 7
// baseline (797.723 us; speedup 1.0000x reference)
//
#include <hip/hip_runtime.h>

#define N_NODES 50000
#define N_EDGES 800000
#define NODE_DIM 128
#define EDGE_DIM 64
#define HIDDEN 256
#define K_E 320   // 2*NODE_DIM + EDGE_DIM
#define K_N 192   // NODE_DIM + EDGE_DIM

typedef __attribute__((ext_vector_type(8))) short bf16x8;
typedef __attribute__((ext_vector_type(4))) float f32x4;
typedef __attribute__((ext_vector_type(16))) float f32x16;
typedef unsigned short u16;
typedef unsigned int u32;

#define MFMA16 __builtin_amdgcn_mfma_f32_16x16x32_bf16
#define MFMA32 __builtin_amdgcn_mfma_f32_32x32x16_bf16

__device__ inline u16 f2bf(float f) {
  u32 u = __builtin_bit_cast(u32, f);
  u += 0x7fffu + ((u >> 16) & 1u);
  return (u16)(u >> 16);
}
__device__ inline float bf2f(u16 u) {
  u32 x = ((u32)u) << 16;
  return __builtin_bit_cast(float, x);
}
__device__ inline u32 pack2(float a, float b) {
  return (u32)f2bf(a) | ((u32)f2bf(b) << 16);
}
__device__ inline void st_bf4(u16* p, float4 v) {
  ushort4 r;
  r.x = f2bf(v.x); r.y = f2bf(v.y); r.z = f2bf(v.z); r.w = f2bf(v.w);
  *reinterpret_cast<ushort4*>(p) = r;
}

// ---------------- weight prep (+ fused degree histogram) ----------------
// w1y: 32x32x16 A-frag order, ht-major: [ht][kb][lane][jj], h=ht*32+(l&31),
//      k=kb*16+(l>>5)*8+jj.
// w2y: layer-2 A-frag order, pi-permuted k so layer-1 D rows feed B-frags
//      in-register: out=t2*32+(l&31), k=kb2*16+(jj&3)+8*(jj>>2)+4*(l>>5).
__global__ void prep_weights(const float* __restrict__ We1, const float* __restrict__ We2,
                             const float* __restrict__ Wn1, const float* __restrict__ Wn2,
                             const float* __restrict__ nf, const int* __restrict__ dst,
                             u16* __restrict__ w1y, u16* __restrict__ w2y,
                             u16* __restrict__ wn1t, u16* __restrict__ wn2t,
                             u16* __restrict__ nfb, int* __restrict__ hist) {
  const int stride = gridDim.x * blockDim.x;
  const int tid = blockIdx.x * blockDim.x + threadIdx.x;
  for (int i = tid; i < HIDDEN * K_E; i += stride) {
    int jj = i & 7;
    int l = (i >> 3) & 63;
    int rem = i % 10240;
    int kb = rem >> 9;
    int ht = i / 10240;
    int h = ht * 32 + (l & 31);
    int k = kb * 16 + (l >> 5) * 8 + jj;
    w1y[i] = f2bf(We1[k * HIDDEN + h]);
  }
  for (int i = tid; i < EDGE_DIM * HIDDEN; i += stride) {
    int jj = i & 7;
    int l = (i >> 3) & 63;
    int t2 = (i >> 9) & 1;
    int kb2 = i >> 10;
    int out = t2 * 32 + (l & 31);
    int hi = l >> 5;
    int k = kb2 * 16 + (jj & 3) + 8 * (jj >> 2) + 4 * hi;
    w2y[i] = f2bf(We2[k * EDGE_DIM + out]);
  }
  for (int i = tid; i < HIDDEN * K_N; i += stride) {
    int n = i / K_N, k = i % K_N;
    wn1t[i] = f2bf(Wn1[k * HIDDEN + n]);
  }
  for (int i = tid; i < NODE_DIM * HIDDEN; i += stride) {
    int n = i / HIDDEN, k = i % HIDDEN;
    wn2t[i] = f2bf(Wn2[k * NODE_DIM + n]);
  }
  {
    const float4* nf4 = reinterpret_cast<const float4*>(nf);
    for (int i = tid; i < N_NODES * NODE_DIM / 4; i += stride)
      st_bf4(&nfb[i * 4], nf4[i]);
  }
  for (int i = tid; i < N_EDGES; i += stride)
    atomicAdd(&hist[dst[i]], 1);
}

// ---------------- CSR build: 3-phase parallel scan ----------------
// Phase partials live in eid[] (dead until scatter_kernel, stream-ordered).
#define NB_SCAN 196   // 196*256 = 50176 >= 50000

__global__ void scanA_kernel(const int* __restrict__ hist, int* __restrict__ eid) {
  __shared__ int red[256];
  int gid = blockIdx.x * 256 + threadIdx.x;
  int v = (gid < N_NODES) ? hist[gid] : 0;
  red[threadIdx.x] = v;
  __syncthreads();
  for (int d = 128; d > 0; d >>= 1) {
    if (threadIdx.x < d) red[threadIdx.x] += red[threadIdx.x + d];
    __syncthreads();
  }
  if (threadIdx.x == 0) eid[blockIdx.x] = red[0];   // bsum[b]
}

__global__ void scanB_kernel(int* __restrict__ eid, int* __restrict__ off) {
  __shared__ int ssum[256];
  int tid = threadIdx.x;
  int v = (tid < NB_SCAN) ? eid[tid] : 0;
  ssum[tid] = v;
  __syncthreads();
  for (int d = 1; d < 256; d <<= 1) {
    int t = (tid >= d) ? ssum[tid - d] : 0;
    __syncthreads();
    ssum[tid] += t;
    __syncthreads();
  }
  if (tid < NB_SCAN) eid[256 + tid] = ssum[tid] - v;   // bpre[b] (exclusive)
  if (tid == 255) off[N_NODES] = ssum[255];            // total edges
}

__global__ void scanC_kernel(const int* __restrict__ hist, const int* __restrict__ eid,
                             int* __restrict__ off, int* __restrict__ cursor) {
  __shared__ int ssum[256];
  int tid = threadIdx.x;
  int gid = blockIdx.x * 256 + tid;
  int base = eid[256 + blockIdx.x];
  int v = (gid < N_NODES) ? hist[gid] : 0;
  ssum[tid] = v;
  __syncthreads();
  for (int d = 1; d < 256; d <<= 1) {
    int t = (tid >= d) ? ssum[tid - d] : 0;
    __syncthreads();
    ssum[tid] += t;
    __syncthreads();
  }
  if (gid < N_NODES) {
    int o = base + ssum[tid] - v;
    off[gid] = o;
    cursor[gid] = o;
  }
}

__global__ void scatter_kernel(const int* __restrict__ dst, int* __restrict__ cursor,
                               int* __restrict__ eid) {
  int e = blockIdx.x * blockDim.x + threadIdx.x;
  if (e < N_EDGES) eid[atomicAdd(&cursor[dst[e]], 1)] = e;
}

// ---------------- edge MLP v5b: 32x32 MFMA, ht-outer, in-register L1->L2 chain --
// Identical body to R6 (verified); launch_bounds bumped to 4 blocks/CU.
__global__ __launch_bounds__(256, 4) void edge_mlp(
    const u16* __restrict__ nfb, const float* __restrict__ ef,
    const int* __restrict__ src, const int* __restrict__ dst,
    const u16* __restrict__ w1y, const float* __restrict__ b1,
    const u16* __restrict__ w2y, const float* __restrict__ b2,
    u16* __restrict__ e_upd, float* __restrict__ out_edge)
{
  __shared__ u16 W1s[2][10240];   // 40KB total

  const int tid = threadIdx.x;
  const int wv = tid >> 6, lane = tid & 63;
  const int ecol = lane & 31;     // edge within wave tile (D col)
  const int hi = lane >> 5;       // k half
  const int e0 = blockIdx.x * 128;
  const int eg = e0 + wv * 32 + ecol;

  // ---- fused edge-feature passthrough (fp32), fully coalesced ----
  {
    const float4* ef4 = reinterpret_cast<const float4*>(ef);
    float4* oe4 = reinterpret_cast<float4*>(out_edge);
    #pragma unroll
    for (int p = 0; p < 8; ++p) {
      size_t i = (size_t)e0 * 16 + p * 256 + tid;
      oe4[i] = ef4[i];
    }
  }

  // ---- gather edge concat features into B-frags (k = kb*16 + hi*8 + jj) ----
  const int si = src[eg] << 7;
  const int di = dst[eg] << 7;
  bf16x8 efr[20];
  #pragma unroll
  for (int kb = 0; kb < 8; ++kb)
    efr[kb] = *reinterpret_cast<const bf16x8*>(nfb + si + kb * 16 + hi * 8);
  #pragma unroll
  for (int kb = 0; kb < 4; ++kb) {
    const float* ep = ef + (size_t)eg * 64 + kb * 16 + hi * 8;
    float4 lo = *reinterpret_cast<const float4*>(ep);
    float4 hv = *reinterpret_cast<const float4*>(ep + 4);
    bf16x8 v;
    v[0] = (short)f2bf(lo.x); v[1] = (short)f2bf(lo.y);
    v[2] = (short)f2bf(lo.z); v[3] = (short)f2bf(lo.w);
    v[4] = (short)f2bf(hv.x); v[5] = (short)f2bf(hv.y);
    v[6] = (short)f2bf(hv.z); v[7] = (short)f2bf(hv.w);
    efr[8 + kb] = v;
  }
  #pragma unroll
  for (int kb = 0; kb < 8; ++kb)
    efr[12 + kb] = *reinterpret_cast<const bf16x8*>(nfb + di + kb * 16 + hi * 8);

  // ---- prologue: stage W1[ht=0] (20KB) ----
  {
    const uint4* s = reinterpret_cast<const uint4*>(w1y);
    uint4* d = reinterpret_cast<uint4*>(W1s[0]);
    #pragma unroll
    for (int j = 0; j < 5; ++j) d[tid + j * 256] = s[tid + j * 256];
  }
  __syncthreads();

  // ---- layer-2 accumulators, bias-initialized (D row map) ----
  f32x16 acc2[2];
  #pragma unroll
  for (int t2 = 0; t2 < 2; ++t2)
    #pragma unroll
    for (int r = 0; r < 16; ++r)
      acc2[t2][r] = b2[t2 * 32 + (r & 3) + 8 * (r >> 2) + 4 * hi];

  // ---- ht loop: 8 tiles of 32 hidden ----
  #pragma unroll
  for (int ht = 0; ht < 8; ++ht) {
    uint4 st[5];
    if (ht < 7) {   // issue next-tile loads early
      const uint4* s = reinterpret_cast<const uint4*>(w1y + (ht + 1) * 10240);
      #pragma unroll
      for (int j = 0; j < 5; ++j) st[j] = s[tid + j * 256];
    }

    // layer 1: acc[h(32) x e(32)] over K=320
    f32x16 acc;
    #pragma unroll
    for (int r = 0; r < 16; ++r)
      acc[r] = b1[ht * 32 + (r & 3) + 8 * (r >> 2) + 4 * hi];
    const u16* Wb = W1s[ht & 1];
    #pragma unroll
    for (int kb = 0; kb < 20; ++kb) {
      bf16x8 wf = *reinterpret_cast<const bf16x8*>(Wb + (kb * 64 + lane) * 8);
      acc = MFMA32(wf, efr[kb], acc, 0, 0, 0);
    }

    // layer 2: relu+pack acc rows -> B-frag slots (pi matches D row layout)
    #pragma unroll
    for (int s2 = 0; s2 < 2; ++s2) {
      bf16x8 hf;
      u32* hw = reinterpret_cast<u32*>(&hf);
      #pragma unroll
      for (int m = 0; m < 4; ++m)
        hw[m] = pack2(fmaxf(acc[s2 * 8 + 2 * m], 0.f),
                      fmaxf(acc[s2 * 8 + 2 * m + 1], 0.f));
      #pragma unroll
      for (int t2 = 0; t2 < 2; ++t2) {
        bf16x8 wf2 = *reinterpret_cast<const bf16x8*>(
            w2y + ((size_t)((ht * 2 + s2) * 2 + t2) * 64 + lane) * 8);
        acc2[t2] = MFMA32(wf2, hf, acc2[t2], 0, 0, 0);
      }
    }

    if (ht < 7) {   // write next tile, one barrier per ht
      uint4* d = reinterpret_cast<uint4*>(W1s[(ht + 1) & 1]);
      #pragma unroll
      for (int j = 0; j < 5; ++j) d[tid + j * 256] = st[j];
      __syncthreads();
    }
  }

  // ---- per-wave bounce (aliases W1s buf0; ht=7 read buf1 -> disjoint) ----
  u16* hb = reinterpret_cast<u16*>(W1s) + wv * 2304;   // 32 rows x 72 u16
  #pragma unroll
  for (int t2 = 0; t2 < 2; ++t2)
    #pragma unroll
    for (int m = 0; m < 8; ++m) {
      int rowb = 2 * (m & 1) + 8 * (m >> 1) + 4 * hi;   // rows rowb, rowb+1
      *reinterpret_cast<u32*>(hb + ecol * 72 + t2 * 32 + rowb) =
          pack2(acc2[t2][2 * m], acc2[t2][2 * m + 1]);
    }
  // same-wave ds_write -> ds_read: compiler inserts lgkmcnt wait
  {
    int er = lane >> 1, half = lane & 1;
    const u16* rp = hb + er * 72 + half * 32;
    uint4 o0 = *reinterpret_cast<const uint4*>(rp + 0);
    uint4 o1 = *reinterpret_cast<const uint4*>(rp + 8);
    uint4 o2 = *reinterpret_cast<const uint4*>(rp + 16);
    uint4 o3 = *reinterpret_cast<const uint4*>(rp + 24);
    uint4* dp = reinterpret_cast<uint4*>(
        e_upd + (size_t)(e0 + wv * 32 + er) * 64 + half * 32);
    dp[0] = o0; dp[1] = o1; dp[2] = o2; dp[3] = o3;
  }
}

// ---------------- per-node message sum (CSR gather), batched eid prefetch ----
__global__ __launch_bounds__(256) void sum_kernel(
    const u16* __restrict__ e_upd, const int* __restrict__ off,
    const int* __restrict__ eid, float* __restrict__ e_sum)
{
  const int grp = threadIdx.x >> 4, l16 = threadIdx.x & 15;
  const int lanebase = (threadIdx.x & 63) & ~15;   // group's first lane in wave
  const int n = blockIdx.x * 16 + grp;             // grid 3125*16 = 50000 exact
  float4 a = {0.f, 0.f, 0.f, 0.f};
  const int s0 = off[n], s1 = off[n + 1];
  for (int base = s0; base < s1; base += 16) {
    int myeid = (base + l16 < s1) ? eid[base + l16] : 0;   // coalesced batch
    int cnt = min(16, s1 - base);
    int t = 0;
    for (; t + 3 < cnt; t += 4) {   // 4-wide MLP on row loads
      int ea = __shfl(myeid, lanebase + t, 64);
      int eb = __shfl(myeid, lanebase + t + 1, 64);
      int ec = __shfl(myeid, lanebase + t + 2, 64);
      int ed = __shfl(myeid, lanebase + t + 3, 64);
      ushort4 va = *reinterpret_cast<const ushort4*>(&e_upd[(size_t)ea * 64 + l16 * 4]);
      ushort4 vb = *reinterpret_cast<const ushort4*>(&e_upd[(size_t)eb * 64 + l16 * 4]);
      ushort4 vc = *reinterpret_cast<const ushort4*>(&e_upd[(size_t)ec * 64 + l16 * 4]);
      ushort4 vd = *reinterpret_cast<const ushort4*>(&e_upd[(size_t)ed * 64 + l16 * 4]);
      a.x += bf2f(va.x) + bf2f(vb.x) + bf2f(vc.x) + bf2f(vd.x);
      a.y += bf2f(va.y) + bf2f(vb.y) + bf2f(vc.y) + bf2f(vd.y);
      a.z += bf2f(va.z) + bf2f(vb.z) + bf2f(vc.z) + bf2f(vd.z);
      a.w += bf2f(va.w) + bf2f(vb.w) + bf2f(vc.w) + bf2f(vd.w);
    }
    for (; t < cnt; ++t) {
      int e = __shfl(myeid, lanebase + t, 64);
      ushort4 v = *reinterpret_cast<const ushort4*>(&e_upd[(size_t)e * 64 + l16 * 4]);
      a.x += bf2f(v.x); a.y += bf2f(v.y);
      a.z += bf2f(v.z); a.w += bf2f(v.w);
    }
  }
  *reinterpret_cast<float4*>(&e_sum[(size_t)n * 64 + l16 * 4]) = a;
}

// ---------------- node MLP + degree gate ----------------
#define SA_N 200
#define SH   264

__global__ __launch_bounds__(256) void node_kernel(
    const float* __restrict__ nf, const float* __restrict__ e_sum,
    const int* __restrict__ hist,
    const u16* __restrict__ w1, const float* __restrict__ b1,
    const u16* __restrict__ w2, const float* __restrict__ b2,
    float* __restrict__ hout)
{
  __shared__ u16 A[64 * SH];
  const int tid = threadIdx.x;
  const int n0 = blockIdx.x * 64;

  const float4* nf4 = reinterpret_cast<const float4*>(nf);
  const float4* es4 = reinterpret_cast<const float4*>(e_sum);

  #pragma unroll
  for (int p = 0; p < 8; ++p) {
    int i = p * 256 + tid;
    int row = i >> 5, c4 = i & 31;
    int rg = min(n0 + row, N_NODES - 1);
    float4 v = nf4[(size_t)rg * 32 + c4];
    st_bf4(&A[row * SA_N + c4 * 4], v);
  }
  #pragma unroll
  for (int p = 0; p < 4; ++p) {
    int i = p * 256 + tid;
    int row = i >> 4, c4 = i & 15;
    int rg = min(n0 + row, N_NODES - 1);
    float4 v = es4[(size_t)rg * 16 + c4];
    st_bf4(&A[row * SA_N + 128 + c4 * 4], v);
  }
  __syncthreads();

  const int wave = tid >> 6, lane = tid & 63;
  const int lr = lane & 15;
  const int lk = (lane >> 4) * 8;

  f32x4 acc[4][4] = {};
  for (int kb = 0; kb < K_N / 32; ++kb) {
    const int ko = kb * 32 + lk;
    bf16x8 a[4], b[4];
    #pragma unroll
    for (int mt = 0; mt < 4; ++mt)
      a[mt] = *reinterpret_cast<const bf16x8*>(&A[(mt * 16 + lr) * SA_N + ko]);
    #pragma unroll
    for (int nt = 0; nt < 4; ++nt)
      b[nt] = *reinterpret_cast<const bf16x8*>(&w1[(size_t)(wave * 64 + nt * 16 + lr) * K_N + ko]);
    #pragma unroll
    for (int mt = 0; mt < 4; ++mt)
      #pragma unroll
      for (int nt = 0; nt < 4; ++nt)
        acc[mt][nt] = MFMA16(a[mt], b[nt], acc[mt][nt], 0, 0, 0);
  }
  __syncthreads();

  u16* H = A;
  #pragma unroll
  for (int mt = 0; mt < 4; ++mt)
    #pragma unroll
    for (int nt = 0; nt < 4; ++nt) {
      int col = wave * 64 + nt * 16 + lr;
      float bias = b1[col];
      #pragma unroll
      for (int j = 0; j < 4; ++j) {
        int row = mt * 16 + (lane >> 4) * 4 + j;
        float h = acc[mt][nt][j] + bias;
        H[row * SH + col] = f2bf(h > 0.f ? h : 0.f);
      }
    }
  __syncthreads();

  f32x4 acc2[8] = {};
  for (int kb = 0; kb < HIDDEN / 32; ++kb) {
    const int ko = kb * 32 + lk;
    bf16x8 a = *reinterpret_cast<const bf16x8*>(&H[(wave * 16 + lr) * SH + ko]);
    #pragma unroll
    for (int nt = 0; nt < 8; ++nt) {
      bf16x8 b = *reinterpret_cast<const bf16x8*>(&w2[(size_t)(nt * 16 + lr) * HIDDEN + ko]);
      acc2[nt] = MFMA16(a, b, acc2[nt], 0, 0, 0);
    }
  }
  #pragma unroll
  for (int nt = 0; nt < 8; ++nt) {
    int col = nt * 16 + lr;
    float bias = b2[col];
    #pragma unroll
    for (int j = 0; j < 4; ++j) {
      int row = wave * 16 + (lane >> 4) * 4 + j;
      int rg = n0 + row;
      if (rg < N_NODES) {
        float v = acc2[nt][j] + bias;
        hout[(size_t)rg * NODE_DIM + col] =
            (hist[rg] != 0) ? v : nf[(size_t)rg * NODE_DIM + col];
      }
    }
  }
}

// ---------------- launcher ----------------
extern "C" void kernel_launch(void* const* d_in, const int* in_sizes, int n_in,
                              void* d_out, int out_size, void* d_ws, size_t ws_size,
                              hipStream_t stream) {
  const float* nf  = (const float*)d_in[0];
  const float* ef  = (const float*)d_in[1];
  const int*   src = (const int*)d_in[2];
  const int*   dst = (const int*)d_in[3];
  const float* We1 = (const float*)d_in[4];
  const float* be1 = (const float*)d_in[5];
  const float* We2 = (const float*)d_in[6];
  const float* be2 = (const float*)d_in[7];
  const float* Wn1 = (const float*)d_in[8];
  const float* bn1 = (const float*)d_in[9];
  const float* Wn2 = (const float*)d_in[10];
  const float* bn2 = (const float*)d_in[11];

  float* hout = (float*)d_out;
  float* out_edge = hout + (size_t)N_NODES * NODE_DIM;

  char* ws = (char*)d_ws;
  int* hist    = (int*)ws;                       // 200,000 B
  int* off     = (int*)(ws + 200000);            // 200,004 B
  int* cursor  = (int*)(ws + 400016);            // 200,000 B
  int* eid     = (int*)(ws + 600016);            // 3,200,000 B (scan partials early)
  u16* e_upd   = (u16*)(ws + 3800016);           // 102,400,000 B
  u16* w1y     = (u16*)(ws + 106200016);         // 163,840 B
  u16* w2y     = (u16*)(ws + 106363856);         // 32,768 B
  u16* wn1t    = (u16*)(ws + 106396624);         // 98,304 B
  u16* wn2t    = (u16*)(ws + 106494928);         // 65,536 B
  u16* nfb     = (u16*)(ws + 106560464);         // 12,800,000 B
  // e_sum (f32, 12.8MB) aliases nfb: nfb consumed only by edge_mlp (stream-
  // ordered before sum_kernel writes e_sum).
  float* e_sum = (float*)(ws + 106560464);

  hipMemsetAsync(hist, 0, 200000, stream);
  prep_weights<<<512, 256, 0, stream>>>(We1, We2, Wn1, Wn2, nf, dst,
                                        w1y, w2y, wn1t, wn2t, nfb, hist);
  scanA_kernel<<<NB_SCAN, 256, 0, stream>>>(hist, eid);
  scanB_kernel<<<1, 256, 0, stream>>>(eid, off);
  scanC_kernel<<<NB_SCAN, 256, 0, stream>>>(hist, eid, off, cursor);
  scatter_kernel<<<(N_EDGES + 255) / 256, 256, 0, stream>>>(dst, cursor, eid);

  edge_mlp<<<N_EDGES / 128, 256, 0, stream>>>(nfb, ef, src, dst, w1y, be1,
                                              w2y, be2, e_upd, out_edge);
  sum_kernel<<<N_NODES / 16, 256, 0, stream>>>(e_upd, off, eid, e_sum);
  node_kernel<<<(N_NODES + 63) / 64, 256, 0, stream>>>(nf, e_sum, hist,
                                                       wn1t, bn1, wn2t, bn2, hout);
}

// Round 8
// 592.520 us; speedup vs baseline: 1.3463x; 1.3463x over previous
//
#include <hip/hip_runtime.h>

#define N_NODES 50000
#define N_EDGES 800000
#define NODE_DIM 128
#define EDGE_DIM 64
#define HIDDEN 256
#define K_E 320   // 2*NODE_DIM + EDGE_DIM
#define K_N 192   // NODE_DIM + EDGE_DIM

typedef __attribute__((ext_vector_type(8))) short bf16x8;
typedef __attribute__((ext_vector_type(4))) float f32x4;
typedef __attribute__((ext_vector_type(16))) float f32x16;
typedef unsigned short u16;
typedef unsigned int u32;

#define MFMA16 __builtin_amdgcn_mfma_f32_16x16x32_bf16
#define MFMA32 __builtin_amdgcn_mfma_f32_32x32x16_bf16

__device__ inline u16 f2bf(float f) {
  u32 u = __builtin_bit_cast(u32, f);
  u += 0x7fffu + ((u >> 16) & 1u);
  return (u16)(u >> 16);
}
__device__ inline float bf2f(u16 u) {
  u32 x = ((u32)u) << 16;
  return __builtin_bit_cast(float, x);
}
__device__ inline u32 pack2(float a, float b) {
  return (u32)f2bf(a) | ((u32)f2bf(b) << 16);
}
__device__ inline void st_bf4(u16* p, float4 v) {
  ushort4 r;
  r.x = f2bf(v.x); r.y = f2bf(v.y); r.z = f2bf(v.z); r.w = f2bf(v.w);
  *reinterpret_cast<ushort4*>(p) = r;
}

// ---------------- weight prep (+ fused degree histogram) ----------------
__global__ void prep_weights(const float* __restrict__ We1, const float* __restrict__ We2,
                             const float* __restrict__ Wn1, const float* __restrict__ Wn2,
                             const float* __restrict__ nf, const int* __restrict__ dst,
                             u16* __restrict__ w1y, u16* __restrict__ w2y,
                             u16* __restrict__ wn1t, u16* __restrict__ wn2t,
                             u16* __restrict__ nfb, int* __restrict__ hist) {
  const int stride = gridDim.x * blockDim.x;
  const int tid = blockIdx.x * blockDim.x + threadIdx.x;
  for (int i = tid; i < HIDDEN * K_E; i += stride) {
    int jj = i & 7;
    int l = (i >> 3) & 63;
    int rem = i % 10240;
    int kb = rem >> 9;
    int ht = i / 10240;
    int h = ht * 32 + (l & 31);
    int k = kb * 16 + (l >> 5) * 8 + jj;
    w1y[i] = f2bf(We1[k * HIDDEN + h]);
  }
  for (int i = tid; i < EDGE_DIM * HIDDEN; i += stride) {
    int jj = i & 7;
    int l = (i >> 3) & 63;
    int t2 = (i >> 9) & 1;
    int kb2 = i >> 10;
    int out = t2 * 32 + (l & 31);
    int hi = l >> 5;
    int k = kb2 * 16 + (jj & 3) + 8 * (jj >> 2) + 4 * hi;
    w2y[i] = f2bf(We2[k * EDGE_DIM + out]);
  }
  for (int i = tid; i < HIDDEN * K_N; i += stride) {
    int n = i / K_N, k = i % K_N;
    wn1t[i] = f2bf(Wn1[k * HIDDEN + n]);
  }
  for (int i = tid; i < NODE_DIM * HIDDEN; i += stride) {
    int n = i / HIDDEN, k = i % HIDDEN;
    wn2t[i] = f2bf(Wn2[k * NODE_DIM + n]);
  }
  {
    const float4* nf4 = reinterpret_cast<const float4*>(nf);
    for (int i = tid; i < N_NODES * NODE_DIM / 4; i += stride)
      st_bf4(&nfb[i * 4], nf4[i]);
  }
  for (int i = tid; i < N_EDGES; i += stride)
    atomicAdd(&hist[dst[i]], 1);
}

// ---------------- CSR build: 3-phase parallel scan ----------------
// Phase partials live in eid[] (dead until scatter_kernel, stream-ordered).
#define NB_SCAN 196   // 196*256 = 50176 >= 50000

__global__ void scanA_kernel(const int* __restrict__ hist, int* __restrict__ eid) {
  __shared__ int red[256];
  int gid = blockIdx.x * 256 + threadIdx.x;
  int v = (gid < N_NODES) ? hist[gid] : 0;
  red[threadIdx.x] = v;
  __syncthreads();
  for (int d = 128; d > 0; d >>= 1) {
    if (threadIdx.x < d) red[threadIdx.x] += red[threadIdx.x + d];
    __syncthreads();
  }
  if (threadIdx.x == 0) eid[blockIdx.x] = red[0];   // bsum[b]
}

__global__ void scanB_kernel(int* __restrict__ eid, int* __restrict__ off) {
  __shared__ int ssum[256];
  int tid = threadIdx.x;
  int v = (tid < NB_SCAN) ? eid[tid] : 0;
  ssum[tid] = v;
  __syncthreads();
  for (int d = 1; d < 256; d <<= 1) {
    int t = (tid >= d) ? ssum[tid - d] : 0;
    __syncthreads();
    ssum[tid] += t;
    __syncthreads();
  }
  if (tid < NB_SCAN) eid[256 + tid] = ssum[tid] - v;   // bpre[b] (exclusive)
  if (tid == 255) off[N_NODES] = ssum[255];            // total
}

__global__ void scanC_kernel(const int* __restrict__ hist, const int* __restrict__ eid,
                             int* __restrict__ off, int* __restrict__ cursor) {
  __shared__ int ssum[256];
  int tid = threadIdx.x;
  int gid = blockIdx.x * 256 + tid;
  int base = eid[256 + blockIdx.x];
  int v = (gid < N_NODES) ? hist[gid] : 0;
  ssum[tid] = v;
  __syncthreads();
  for (int d = 1; d < 256; d <<= 1) {
    int t = (tid >= d) ? ssum[tid - d] : 0;
    __syncthreads();
    ssum[tid] += t;
    __syncthreads();
  }
  if (gid < N_NODES) {
    int o = base + ssum[tid] - v;
    off[gid] = o;
    cursor[gid] = o;
  }
}

// also emits csr_src/csr_dst so the edge kernel's index loads are coalesced
__global__ void scatter_kernel(const int* __restrict__ src, const int* __restrict__ dst,
                               int* __restrict__ cursor, int* __restrict__ eid,
                               int* __restrict__ csr_src, int* __restrict__ csr_dst) {
  int e = blockIdx.x * blockDim.x + threadIdx.x;
  if (e < N_EDGES) {
    int d = dst[e];
    int pos = atomicAdd(&cursor[d], 1);
    eid[pos] = e;
    csr_src[pos] = src[e];
    csr_dst[pos] = d;
  }
}

// ---------------- edge MLP v6: CSR-ordered, fused segment-sum ----------------
// MFMA core identical to R6 (verified, 437us @ (256,3)). Changes:
//  - lanes process CSR positions (eid-gathered features; dst rows are runs)
//  - layer-2 f32 acc -> padded LDS bounce [128 pos][65 f32]
//  - wave-uniform run-reduction, one f32 atomicAdd per (run x dim) to e_sum
//  - no e_upd write at all
__global__ __launch_bounds__(256, 3) void edge_mlp(
    const u16* __restrict__ nfb, const float* __restrict__ ef,
    const int* __restrict__ eid, const int* __restrict__ csr_src,
    const int* __restrict__ csr_dst,
    const u16* __restrict__ w1y, const float* __restrict__ b1,
    const u16* __restrict__ w2y, const float* __restrict__ b2,
    float* __restrict__ e_sum, float* __restrict__ out_edge)
{
  __shared__ u16 W1s[2][10240];   // 40KB; aliased as f32 bounce after ht loop
  __shared__ int dsts[128];

  const int tid = threadIdx.x;
  const int wv = tid >> 6, lane = tid & 63;
  const int ecol = lane & 31;     // CSR position within wave tile (D col)
  const int hi = lane >> 5;       // k half
  const int e0 = blockIdx.x * 128;
  const int pos = e0 + wv * 32 + ecol;

  // ---- fused edge-feature passthrough (identity, fp32, fully coalesced) ----
  {
    const float4* ef4 = reinterpret_cast<const float4*>(ef);
    float4* oe4 = reinterpret_cast<float4*>(out_edge);
    #pragma unroll
    for (int p = 0; p < 8; ++p) {
      size_t i = (size_t)e0 * 16 + p * 256 + tid;
      oe4[i] = ef4[i];
    }
  }

  // ---- CSR indices (coalesced) ----
  const int e    = eid[pos];
  const int srcn = csr_src[pos];
  const int dstn = csr_dst[pos];
  dsts[wv * 32 + ecol] = dstn;   // both hi halves write same value (benign)

  // ---- gather concat features into B-frags (k = kb*16 + hi*8 + jj) ----
  const int si = srcn << 7;
  const int di = dstn << 7;   // run-local: mostly L1 broadcast within the wave
  bf16x8 efr[20];
  #pragma unroll
  for (int kb = 0; kb < 8; ++kb)
    efr[kb] = *reinterpret_cast<const bf16x8*>(nfb + si + kb * 16 + hi * 8);
  #pragma unroll
  for (int kb = 0; kb < 4; ++kb) {
    const float* ep = ef + (size_t)e * 64 + kb * 16 + hi * 8;
    float4 lo = *reinterpret_cast<const float4*>(ep);
    float4 hv = *reinterpret_cast<const float4*>(ep + 4);
    bf16x8 v;
    v[0] = (short)f2bf(lo.x); v[1] = (short)f2bf(lo.y);
    v[2] = (short)f2bf(lo.z); v[3] = (short)f2bf(lo.w);
    v[4] = (short)f2bf(hv.x); v[5] = (short)f2bf(hv.y);
    v[6] = (short)f2bf(hv.z); v[7] = (short)f2bf(hv.w);
    efr[8 + kb] = v;
  }
  #pragma unroll
  for (int kb = 0; kb < 8; ++kb)
    efr[12 + kb] = *reinterpret_cast<const bf16x8*>(nfb + di + kb * 16 + hi * 8);

  // ---- prologue: stage W1[ht=0] (20KB) ----
  {
    const uint4* s = reinterpret_cast<const uint4*>(w1y);
    uint4* d = reinterpret_cast<uint4*>(W1s[0]);
    #pragma unroll
    for (int j = 0; j < 5; ++j) d[tid + j * 256] = s[tid + j * 256];
  }
  __syncthreads();

  // ---- layer-2 accumulators, bias-initialized (D row map) ----
  f32x16 acc2[2];
  #pragma unroll
  for (int t2 = 0; t2 < 2; ++t2)
    #pragma unroll
    for (int r = 0; r < 16; ++r)
      acc2[t2][r] = b2[t2 * 32 + (r & 3) + 8 * (r >> 2) + 4 * hi];

  // ---- ht loop: 8 tiles of 32 hidden (identical to R6) ----
  #pragma unroll
  for (int ht = 0; ht < 8; ++ht) {
    uint4 st[5];
    if (ht < 7) {
      const uint4* s = reinterpret_cast<const uint4*>(w1y + (ht + 1) * 10240);
      #pragma unroll
      for (int j = 0; j < 5; ++j) st[j] = s[tid + j * 256];
    }

    f32x16 acc;
    #pragma unroll
    for (int r = 0; r < 16; ++r)
      acc[r] = b1[ht * 32 + (r & 3) + 8 * (r >> 2) + 4 * hi];
    const u16* Wb = W1s[ht & 1];
    #pragma unroll
    for (int kb = 0; kb < 20; ++kb) {
      bf16x8 wf = *reinterpret_cast<const bf16x8*>(Wb + (kb * 64 + lane) * 8);
      acc = MFMA32(wf, efr[kb], acc, 0, 0, 0);
    }

    #pragma unroll
    for (int s2 = 0; s2 < 2; ++s2) {
      bf16x8 hf;
      u32* hw = reinterpret_cast<u32*>(&hf);
      #pragma unroll
      for (int m = 0; m < 4; ++m)
        hw[m] = pack2(fmaxf(acc[s2 * 8 + 2 * m], 0.f),
                      fmaxf(acc[s2 * 8 + 2 * m + 1], 0.f));
      #pragma unroll
      for (int t2 = 0; t2 < 2; ++t2) {
        bf16x8 wf2 = *reinterpret_cast<const bf16x8*>(
            w2y + ((size_t)((ht * 2 + s2) * 2 + t2) * 64 + lane) * 8);
        acc2[t2] = MFMA32(wf2, hf, acc2[t2], 0, 0, 0);
      }
    }

    if (ht < 7) {
      uint4* d = reinterpret_cast<uint4*>(W1s[(ht + 1) & 1]);
      #pragma unroll
      for (int j = 0; j < 5; ++j) d[tid + j * 256] = st[j];
      __syncthreads();
    }
  }

  __syncthreads();   // all waves done reading W1s before bounce aliasing

  // ---- f32 message bounce: [128 pos][stride 65] (bank-conflict-free) ----
  float* bounce = reinterpret_cast<float*>(W1s);
  {
    const int lp = wv * 32 + ecol;   // local position
    #pragma unroll
    for (int t2 = 0; t2 < 2; ++t2)
      #pragma unroll
      for (int r = 0; r < 16; ++r) {
        int o = t2 * 32 + (r & 3) + 8 * (r >> 2) + 4 * hi;
        bounce[lp * 65 + o] = acc2[t2][r];
      }
  }
  __syncthreads();

  // ---- wave-uniform run-reduction over this wave's 32 positions ----
  {
    const int d = lane;            // dim 0..63
    const int base = wv * 32;      // strip of 32 local positions
    float s = bounce[base * 65 + d];
    int cur = dsts[base];
    #pragma unroll 4
    for (int i = 1; i < 32; ++i) {
      int nx = dsts[base + i];     // wave-uniform
      float v = bounce[(base + i) * 65 + d];
      if (nx == cur) {
        s += v;
      } else {
        atomicAdd(&e_sum[(size_t)cur * 64 + d], s);
        cur = nx;
        s = v;
      }
    }
    atomicAdd(&e_sum[(size_t)cur * 64 + d], s);
  }
}

// ---------------- node MLP + degree gate ----------------
#define SA_N 200
#define SH   264

__global__ __launch_bounds__(256) void node_kernel(
    const float* __restrict__ nf, const float* __restrict__ e_sum,
    const int* __restrict__ hist,
    const u16* __restrict__ w1, const float* __restrict__ b1,
    const u16* __restrict__ w2, const float* __restrict__ b2,
    float* __restrict__ hout)
{
  __shared__ u16 A[64 * SH];
  const int tid = threadIdx.x;
  const int n0 = blockIdx.x * 64;

  const float4* nf4 = reinterpret_cast<const float4*>(nf);
  const float4* es4 = reinterpret_cast<const float4*>(e_sum);

  #pragma unroll
  for (int p = 0; p < 8; ++p) {
    int i = p * 256 + tid;
    int row = i >> 5, c4 = i & 31;
    int rg = min(n0 + row, N_NODES - 1);
    float4 v = nf4[(size_t)rg * 32 + c4];
    st_bf4(&A[row * SA_N + c4 * 4], v);
  }
  #pragma unroll
  for (int p = 0; p < 4; ++p) {
    int i = p * 256 + tid;
    int row = i >> 4, c4 = i & 15;
    int rg = min(n0 + row, N_NODES - 1);
    float4 v = es4[(size_t)rg * 16 + c4];
    st_bf4(&A[row * SA_N + 128 + c4 * 4], v);
  }
  __syncthreads();

  const int wave = tid >> 6, lane = tid & 63;
  const int lr = lane & 15;
  const int lk = (lane >> 4) * 8;

  f32x4 acc[4][4] = {};
  for (int kb = 0; kb < K_N / 32; ++kb) {
    const int ko = kb * 32 + lk;
    bf16x8 a[4], b[4];
    #pragma unroll
    for (int mt = 0; mt < 4; ++mt)
      a[mt] = *reinterpret_cast<const bf16x8*>(&A[(mt * 16 + lr) * SA_N + ko]);
    #pragma unroll
    for (int nt = 0; nt < 4; ++nt)
      b[nt] = *reinterpret_cast<const bf16x8*>(&w1[(size_t)(wave * 64 + nt * 16 + lr) * K_N + ko]);
    #pragma unroll
    for (int mt = 0; mt < 4; ++mt)
      #pragma unroll
      for (int nt = 0; nt < 4; ++nt)
        acc[mt][nt] = MFMA16(a[mt], b[nt], acc[mt][nt], 0, 0, 0);
  }
  __syncthreads();

  u16* H = A;
  #pragma unroll
  for (int mt = 0; mt < 4; ++mt)
    #pragma unroll
    for (int nt = 0; nt < 4; ++nt) {
      int col = wave * 64 + nt * 16 + lr;
      float bias = b1[col];
      #pragma unroll
      for (int j = 0; j < 4; ++j) {
        int row = mt * 16 + (lane >> 4) * 4 + j;
        float h = acc[mt][nt][j] + bias;
        H[row * SH + col] = f2bf(h > 0.f ? h : 0.f);
      }
    }
  __syncthreads();

  f32x4 acc2[8] = {};
  for (int kb = 0; kb < HIDDEN / 32; ++kb) {
    const int ko = kb * 32 + lk;
    bf16x8 a = *reinterpret_cast<const bf16x8*>(&H[(wave * 16 + lr) * SH + ko]);
    #pragma unroll
    for (int nt = 0; nt < 8; ++nt) {
      bf16x8 b = *reinterpret_cast<const bf16x8*>(&w2[(size_t)(nt * 16 + lr) * HIDDEN + ko]);
      acc2[nt] = MFMA16(a, b, acc2[nt], 0, 0, 0);
    }
  }
  #pragma unroll
  for (int nt = 0; nt < 8; ++nt) {
    int col = nt * 16 + lr;
    float bias = b2[col];
    #pragma unroll
    for (int j = 0; j < 4; ++j) {
      int row = wave * 16 + (lane >> 4) * 4 + j;
      int rg = n0 + row;
      if (rg < N_NODES) {
        float v = acc2[nt][j] + bias;
        hout[(size_t)rg * NODE_DIM + col] =
            (hist[rg] != 0) ? v : nf[(size_t)rg * NODE_DIM + col];
      }
    }
  }
}

// ---------------- launcher ----------------
extern "C" void kernel_launch(void* const* d_in, const int* in_sizes, int n_in,
                              void* d_out, int out_size, void* d_ws, size_t ws_size,
                              hipStream_t stream) {
  const float* nf  = (const float*)d_in[0];
  const float* ef  = (const float*)d_in[1];
  const int*   src = (const int*)d_in[2];
  const int*   dst = (const int*)d_in[3];
  const float* We1 = (const float*)d_in[4];
  const float* be1 = (const float*)d_in[5];
  const float* We2 = (const float*)d_in[6];
  const float* be2 = (const float*)d_in[7];
  const float* Wn1 = (const float*)d_in[8];
  const float* bn1 = (const float*)d_in[9];
  const float* Wn2 = (const float*)d_in[10];
  const float* bn2 = (const float*)d_in[11];

  float* hout = (float*)d_out;
  float* out_edge = hout + (size_t)N_NODES * NODE_DIM;

  char* ws = (char*)d_ws;
  int*   hist    = (int*)ws;                     // 200,000 B
  int*   off     = (int*)(ws + 200000);          // 200,004 B
  int*   cursor  = (int*)(ws + 400016);          // 200,000 B
  int*   eid     = (int*)(ws + 600016);          // 3,200,000 B (scan partials early)
  int*   csr_src = (int*)(ws + 3800016);         // 3,200,000 B
  int*   csr_dst = (int*)(ws + 7000016);         // 3,200,000 B
  float* e_sum   = (float*)(ws + 10200016);      // 12,800,000 B (f32)
  u16*   w1y     = (u16*)(ws + 23000016);        // 163,840 B
  u16*   w2y     = (u16*)(ws + 23163856);        // 32,768 B
  u16*   wn1t    = (u16*)(ws + 23196624);        // 98,304 B
  u16*   wn2t    = (u16*)(ws + 23294928);        // 65,536 B
  u16*   nfb     = (u16*)(ws + 23360464);        // 12,800,000 B  (end ~36.2 MB)

  hipMemsetAsync(hist, 0, 200000, stream);
  hipMemsetAsync(e_sum, 0, 12800000, stream);
  prep_weights<<<512, 256, 0, stream>>>(We1, We2, Wn1, Wn2, nf, dst,
                                        w1y, w2y, wn1t, wn2t, nfb, hist);
  scanA_kernel<<<NB_SCAN, 256, 0, stream>>>(hist, eid);
  scanB_kernel<<<1, 256, 0, stream>>>(eid, off);
  scanC_kernel<<<NB_SCAN, 256, 0, stream>>>(hist, eid, off, cursor);
  scatter_kernel<<<(N_EDGES + 255) / 256, 256, 0, stream>>>(src, dst, cursor, eid,
                                                            csr_src, csr_dst);

  edge_mlp<<<N_EDGES / 128, 256, 0, stream>>>(nfb, ef, eid, csr_src, csr_dst,
                                              w1y, be1, w2y, be2, e_sum, out_edge);
  node_kernel<<<(N_NODES + 63) / 64, 256, 0, stream>>>(nf, e_sum, hist,
                                                       wn1t, bn1, wn2t, bn2, hout);
}

// Round 9
// 591.139 us; speedup vs baseline: 1.3495x; 1.0023x over previous
//
#include <hip/hip_runtime.h>

#define N_NODES 50000
#define N_EDGES 800000
#define NODE_DIM 128
#define EDGE_DIM 64
#define HIDDEN 256
#define K_E 320   // 2*NODE_DIM + EDGE_DIM
#define K_N 192   // NODE_DIM + EDGE_DIM

typedef __attribute__((ext_vector_type(8))) short bf16x8;
typedef __attribute__((ext_vector_type(4))) float f32x4;
typedef __attribute__((ext_vector_type(16))) float f32x16;
typedef unsigned short u16;
typedef unsigned int u32;

#define MFMA16 __builtin_amdgcn_mfma_f32_16x16x32_bf16
#define MFMA32 __builtin_amdgcn_mfma_f32_32x32x16_bf16

__device__ inline u16 f2bf(float f) {
  u32 u = __builtin_bit_cast(u32, f);
  u += 0x7fffu + ((u >> 16) & 1u);
  return (u16)(u >> 16);
}
__device__ inline float bf2f(u16 u) {
  u32 x = ((u32)u) << 16;
  return __builtin_bit_cast(float, x);
}
__device__ inline u32 pack2(float a, float b) {
  return (u32)f2bf(a) | ((u32)f2bf(b) << 16);
}
__device__ inline void st_bf4(u16* p, float4 v) {
  ushort4 r;
  r.x = f2bf(v.x); r.y = f2bf(v.y); r.z = f2bf(v.z); r.w = f2bf(v.w);
  *reinterpret_cast<ushort4*>(p) = r;
}

// ---------------- weight prep (+ fused degree histogram) ----------------
__global__ void prep_weights(const float* __restrict__ We1, const float* __restrict__ We2,
                             const float* __restrict__ Wn1, const float* __restrict__ Wn2,
                             const float* __restrict__ nf, const int* __restrict__ dst,
                             u16* __restrict__ w1y, u16* __restrict__ w2y,
                             u16* __restrict__ wn1t, u16* __restrict__ wn2t,
                             u16* __restrict__ nfb, int* __restrict__ hist) {
  const int stride = gridDim.x * blockDim.x;
  const int tid = blockIdx.x * blockDim.x + threadIdx.x;
  for (int i = tid; i < HIDDEN * K_E; i += stride) {
    int jj = i & 7;
    int l = (i >> 3) & 63;
    int rem = i % 10240;
    int kb = rem >> 9;
    int ht = i / 10240;
    int h = ht * 32 + (l & 31);
    int k = kb * 16 + (l >> 5) * 8 + jj;
    w1y[i] = f2bf(We1[k * HIDDEN + h]);
  }
  for (int i = tid; i < EDGE_DIM * HIDDEN; i += stride) {
    int jj = i & 7;
    int l = (i >> 3) & 63;
    int t2 = (i >> 9) & 1;
    int kb2 = i >> 10;
    int out = t2 * 32 + (l & 31);
    int hi = l >> 5;
    int k = kb2 * 16 + (jj & 3) + 8 * (jj >> 2) + 4 * hi;
    w2y[i] = f2bf(We2[k * EDGE_DIM + out]);
  }
  for (int i = tid; i < HIDDEN * K_N; i += stride) {
    int n = i / K_N, k = i % K_N;
    wn1t[i] = f2bf(Wn1[k * HIDDEN + n]);
  }
  for (int i = tid; i < NODE_DIM * HIDDEN; i += stride) {
    int n = i / HIDDEN, k = i % HIDDEN;
    wn2t[i] = f2bf(Wn2[k * NODE_DIM + n]);
  }
  {
    const float4* nf4 = reinterpret_cast<const float4*>(nf);
    for (int i = tid; i < N_NODES * NODE_DIM / 4; i += stride)
      st_bf4(&nfb[i * 4], nf4[i]);
  }
  for (int i = tid; i < N_EDGES; i += stride)
    atomicAdd(&hist[dst[i]], 1);
}

// ---------------- CSR build: 3-phase parallel scan ----------------
// Phase partials live in eid[] (dead until scatter_kernel, stream-ordered).
#define NB_SCAN 196   // 196*256 = 50176 >= 50000

__global__ void scanA_kernel(const int* __restrict__ hist, int* __restrict__ eid) {
  __shared__ int red[256];
  int gid = blockIdx.x * 256 + threadIdx.x;
  int v = (gid < N_NODES) ? hist[gid] : 0;
  red[threadIdx.x] = v;
  __syncthreads();
  for (int d = 128; d > 0; d >>= 1) {
    if (threadIdx.x < d) red[threadIdx.x] += red[threadIdx.x + d];
    __syncthreads();
  }
  if (threadIdx.x == 0) eid[blockIdx.x] = red[0];   // bsum[b]
}

__global__ void scanB_kernel(int* __restrict__ eid, int* __restrict__ off) {
  __shared__ int ssum[256];
  int tid = threadIdx.x;
  int v = (tid < NB_SCAN) ? eid[tid] : 0;
  ssum[tid] = v;
  __syncthreads();
  for (int d = 1; d < 256; d <<= 1) {
    int t = (tid >= d) ? ssum[tid - d] : 0;
    __syncthreads();
    ssum[tid] += t;
    __syncthreads();
  }
  if (tid < NB_SCAN) eid[256 + tid] = ssum[tid] - v;   // bpre[b] (exclusive)
  if (tid == 255) off[N_NODES] = ssum[255];            // total
}

__global__ void scanC_kernel(const int* __restrict__ hist, const int* __restrict__ eid,
                             int* __restrict__ off, int* __restrict__ cursor) {
  __shared__ int ssum[256];
  int tid = threadIdx.x;
  int gid = blockIdx.x * 256 + tid;
  int base = eid[256 + blockIdx.x];
  int v = (gid < N_NODES) ? hist[gid] : 0;
  ssum[tid] = v;
  __syncthreads();
  for (int d = 1; d < 256; d <<= 1) {
    int t = (tid >= d) ? ssum[tid - d] : 0;
    __syncthreads();
    ssum[tid] += t;
    __syncthreads();
  }
  if (gid < N_NODES) {
    int o = base + ssum[tid] - v;
    off[gid] = o;
    cursor[gid] = o;
  }
}

// also emits csr_src/csr_dst so the edge kernel's index loads are coalesced
__global__ void scatter_kernel(const int* __restrict__ src, const int* __restrict__ dst,
                               int* __restrict__ cursor, int* __restrict__ eid,
                               int* __restrict__ csr_src, int* __restrict__ csr_dst) {
  int e = blockIdx.x * blockDim.x + threadIdx.x;
  if (e < N_EDGES) {
    int d = dst[e];
    int pos = atomicAdd(&cursor[d], 1);
    eid[pos] = e;
    csr_src[pos] = src[e];
    csr_dst[pos] = d;
  }
}

// ---------------- edge MLP v6b: CSR-ordered, fused segment-sum ----------------
// Identical MFMA core to R8. Change: dsts[] LDS removed (shfl on dstn instead)
// -> LDS exactly 40960 B = 160KB/4 -> 4 blocks/CU if regs stay at 128 total.
__global__ __launch_bounds__(256, 3) void edge_mlp(
    const u16* __restrict__ nfb, const float* __restrict__ ef,
    const int* __restrict__ eid, const int* __restrict__ csr_src,
    const int* __restrict__ csr_dst,
    const u16* __restrict__ w1y, const float* __restrict__ b1,
    const u16* __restrict__ w2y, const float* __restrict__ b2,
    float* __restrict__ e_sum, float* __restrict__ out_edge)
{
  __shared__ u16 W1s[2][10240];   // 40960 B exactly; aliased as f32 bounce later

  const int tid = threadIdx.x;
  const int wv = tid >> 6, lane = tid & 63;
  const int ecol = lane & 31;     // CSR position within wave tile (D col)
  const int hi = lane >> 5;       // k half
  const int e0 = blockIdx.x * 128;
  const int pos = e0 + wv * 32 + ecol;

  // ---- fused edge-feature passthrough (identity, fp32, fully coalesced) ----
  {
    const float4* ef4 = reinterpret_cast<const float4*>(ef);
    float4* oe4 = reinterpret_cast<float4*>(out_edge);
    #pragma unroll
    for (int p = 0; p < 8; ++p) {
      size_t i = (size_t)e0 * 16 + p * 256 + tid;
      oe4[i] = ef4[i];
    }
  }

  // ---- CSR indices (coalesced) ----
  const int e    = eid[pos];
  const int srcn = csr_src[pos];
  const int dstn = csr_dst[pos];   // kept in register; shfl'd in the epilogue

  // ---- gather concat features into B-frags (k = kb*16 + hi*8 + jj) ----
  const int si = srcn << 7;
  const int di = dstn << 7;   // run-local: mostly L1/L2 broadcast within wave
  bf16x8 efr[20];
  #pragma unroll
  for (int kb = 0; kb < 8; ++kb)
    efr[kb] = *reinterpret_cast<const bf16x8*>(nfb + si + kb * 16 + hi * 8);
  #pragma unroll
  for (int kb = 0; kb < 4; ++kb) {
    const float* ep = ef + (size_t)e * 64 + kb * 16 + hi * 8;
    float4 lo = *reinterpret_cast<const float4*>(ep);
    float4 hv = *reinterpret_cast<const float4*>(ep + 4);
    bf16x8 v;
    v[0] = (short)f2bf(lo.x); v[1] = (short)f2bf(lo.y);
    v[2] = (short)f2bf(lo.z); v[3] = (short)f2bf(lo.w);
    v[4] = (short)f2bf(hv.x); v[5] = (short)f2bf(hv.y);
    v[6] = (short)f2bf(hv.z); v[7] = (short)f2bf(hv.w);
    efr[8 + kb] = v;
  }
  #pragma unroll
  for (int kb = 0; kb < 8; ++kb)
    efr[12 + kb] = *reinterpret_cast<const bf16x8*>(nfb + di + kb * 16 + hi * 8);

  // ---- prologue: stage W1[ht=0] (20KB) ----
  {
    const uint4* s = reinterpret_cast<const uint4*>(w1y);
    uint4* d = reinterpret_cast<uint4*>(W1s[0]);
    #pragma unroll
    for (int j = 0; j < 5; ++j) d[tid + j * 256] = s[tid + j * 256];
  }
  __syncthreads();

  // ---- layer-2 accumulators, bias-initialized (D row map) ----
  f32x16 acc2[2];
  #pragma unroll
  for (int t2 = 0; t2 < 2; ++t2)
    #pragma unroll
    for (int r = 0; r < 16; ++r)
      acc2[t2][r] = b2[t2 * 32 + (r & 3) + 8 * (r >> 2) + 4 * hi];

  // ---- ht loop: 8 tiles of 32 hidden (identical to R8) ----
  #pragma unroll
  for (int ht = 0; ht < 8; ++ht) {
    uint4 st[5];
    if (ht < 7) {
      const uint4* s = reinterpret_cast<const uint4*>(w1y + (ht + 1) * 10240);
      #pragma unroll
      for (int j = 0; j < 5; ++j) st[j] = s[tid + j * 256];
    }

    f32x16 acc;
    #pragma unroll
    for (int r = 0; r < 16; ++r)
      acc[r] = b1[ht * 32 + (r & 3) + 8 * (r >> 2) + 4 * hi];
    const u16* Wb = W1s[ht & 1];
    #pragma unroll
    for (int kb = 0; kb < 20; ++kb) {
      bf16x8 wf = *reinterpret_cast<const bf16x8*>(Wb + (kb * 64 + lane) * 8);
      acc = MFMA32(wf, efr[kb], acc, 0, 0, 0);
    }

    #pragma unroll
    for (int s2 = 0; s2 < 2; ++s2) {
      bf16x8 hf;
      u32* hw = reinterpret_cast<u32*>(&hf);
      #pragma unroll
      for (int m = 0; m < 4; ++m)
        hw[m] = pack2(fmaxf(acc[s2 * 8 + 2 * m], 0.f),
                      fmaxf(acc[s2 * 8 + 2 * m + 1], 0.f));
      #pragma unroll
      for (int t2 = 0; t2 < 2; ++t2) {
        bf16x8 wf2 = *reinterpret_cast<const bf16x8*>(
            w2y + ((size_t)((ht * 2 + s2) * 2 + t2) * 64 + lane) * 8);
        acc2[t2] = MFMA32(wf2, hf, acc2[t2], 0, 0, 0);
      }
    }

    if (ht < 7) {
      uint4* d = reinterpret_cast<uint4*>(W1s[(ht + 1) & 1]);
      #pragma unroll
      for (int j = 0; j < 5; ++j) d[tid + j * 256] = st[j];
      __syncthreads();
    }
  }

  __syncthreads();   // all waves done reading W1s before bounce aliasing

  // ---- f32 message bounce: [128 pos][stride 65] (bank-conflict-free) ----
  float* bounce = reinterpret_cast<float*>(W1s);
  {
    const int lp = wv * 32 + ecol;   // local position
    #pragma unroll
    for (int t2 = 0; t2 < 2; ++t2)
      #pragma unroll
      for (int r = 0; r < 16; ++r) {
        int o = t2 * 32 + (r & 3) + 8 * (r >> 2) + 4 * hi;
        bounce[lp * 65 + o] = acc2[t2][r];
      }
  }
  __syncthreads();

  // ---- wave-uniform run-reduction over this wave's 32 positions ----
  // dst ids come from the wave's own dstn registers via shfl (lane i and
  // i+32 hold the same value, so shfl(dstn, i) is well-defined for i<32).
  {
    const int d = lane;            // dim 0..63
    const int base = wv * 32;      // strip of 32 local positions
    float s = bounce[base * 65 + d];
    int cur = __shfl(dstn, 0, 64);
    #pragma unroll 4
    for (int i = 1; i < 32; ++i) {
      int nx = __shfl(dstn, i, 64);   // wave-uniform
      float v = bounce[(base + i) * 65 + d];
      if (nx == cur) {
        s += v;
      } else {
        atomicAdd(&e_sum[(size_t)cur * 64 + d], s);
        cur = nx;
        s = v;
      }
    }
    atomicAdd(&e_sum[(size_t)cur * 64 + d], s);
  }
}

// ---------------- node MLP + degree gate ----------------
#define SA_N 200
#define SH   264

__global__ __launch_bounds__(256) void node_kernel(
    const float* __restrict__ nf, const float* __restrict__ e_sum,
    const int* __restrict__ hist,
    const u16* __restrict__ w1, const float* __restrict__ b1,
    const u16* __restrict__ w2, const float* __restrict__ b2,
    float* __restrict__ hout)
{
  __shared__ u16 A[64 * SH];
  const int tid = threadIdx.x;
  const int n0 = blockIdx.x * 64;

  const float4* nf4 = reinterpret_cast<const float4*>(nf);
  const float4* es4 = reinterpret_cast<const float4*>(e_sum);

  #pragma unroll
  for (int p = 0; p < 8; ++p) {
    int i = p * 256 + tid;
    int row = i >> 5, c4 = i & 31;
    int rg = min(n0 + row, N_NODES - 1);
    float4 v = nf4[(size_t)rg * 32 + c4];
    st_bf4(&A[row * SA_N + c4 * 4], v);
  }
  #pragma unroll
  for (int p = 0; p < 4; ++p) {
    int i = p * 256 + tid;
    int row = i >> 4, c4 = i & 15;
    int rg = min(n0 + row, N_NODES - 1);
    float4 v = es4[(size_t)rg * 16 + c4];
    st_bf4(&A[row * SA_N + 128 + c4 * 4], v);
  }
  __syncthreads();

  const int wave = tid >> 6, lane = tid & 63;
  const int lr = lane & 15;
  const int lk = (lane >> 4) * 8;

  f32x4 acc[4][4] = {};
  for (int kb = 0; kb < K_N / 32; ++kb) {
    const int ko = kb * 32 + lk;
    bf16x8 a[4], b[4];
    #pragma unroll
    for (int mt = 0; mt < 4; ++mt)
      a[mt] = *reinterpret_cast<const bf16x8*>(&A[(mt * 16 + lr) * SA_N + ko]);
    #pragma unroll
    for (int nt = 0; nt < 4; ++nt)
      b[nt] = *reinterpret_cast<const bf16x8*>(&w1[(size_t)(wave * 64 + nt * 16 + lr) * K_N + ko]);
    #pragma unroll
    for (int mt = 0; mt < 4; ++mt)
      #pragma unroll
      for (int nt = 0; nt < 4; ++nt)
        acc[mt][nt] = MFMA16(a[mt], b[nt], acc[mt][nt], 0, 0, 0);
  }
  __syncthreads();

  u16* H = A;
  #pragma unroll
  for (int mt = 0; mt < 4; ++mt)
    #pragma unroll
    for (int nt = 0; nt < 4; ++nt) {
      int col = wave * 64 + nt * 16 + lr;
      float bias = b1[col];
      #pragma unroll
      for (int j = 0; j < 4; ++j) {
        int row = mt * 16 + (lane >> 4) * 4 + j;
        float h = acc[mt][nt][j] + bias;
        H[row * SH + col] = f2bf(h > 0.f ? h : 0.f);
      }
    }
  __syncthreads();

  f32x4 acc2[8] = {};
  for (int kb = 0; kb < HIDDEN / 32; ++kb) {
    const int ko = kb * 32 + lk;
    bf16x8 a = *reinterpret_cast<const bf16x8*>(&H[(wave * 16 + lr) * SH + ko]);
    #pragma unroll
    for (int nt = 0; nt < 8; ++nt) {
      bf16x8 b = *reinterpret_cast<const bf16x8*>(&w2[(size_t)(nt * 16 + lr) * HIDDEN + ko]);
      acc2[nt] = MFMA16(a, b, acc2[nt], 0, 0, 0);
    }
  }
  #pragma unroll
  for (int nt = 0; nt < 8; ++nt) {
    int col = nt * 16 + lr;
    float bias = b2[col];
    #pragma unroll
    for (int j = 0; j < 4; ++j) {
      int row = wave * 16 + (lane >> 4) * 4 + j;
      int rg = n0 + row;
      if (rg < N_NODES) {
        float v = acc2[nt][j] + bias;
        hout[(size_t)rg * NODE_DIM + col] =
            (hist[rg] != 0) ? v : nf[(size_t)rg * NODE_DIM + col];
      }
    }
  }
}

// ---------------- launcher ----------------
extern "C" void kernel_launch(void* const* d_in, const int* in_sizes, int n_in,
                              void* d_out, int out_size, void* d_ws, size_t ws_size,
                              hipStream_t stream) {
  const float* nf  = (const float*)d_in[0];
  const float* ef  = (const float*)d_in[1];
  const int*   src = (const int*)d_in[2];
  const int*   dst = (const int*)d_in[3];
  const float* We1 = (const float*)d_in[4];
  const float* be1 = (const float*)d_in[5];
  const float* We2 = (const float*)d_in[6];
  const float* be2 = (const float*)d_in[7];
  const float* Wn1 = (const float*)d_in[8];
  const float* bn1 = (const float*)d_in[9];
  const float* Wn2 = (const float*)d_in[10];
  const float* bn2 = (const float*)d_in[11];

  float* hout = (float*)d_out;
  float* out_edge = hout + (size_t)N_NODES * NODE_DIM;

  char* ws = (char*)d_ws;
  int*   hist    = (int*)ws;                     // 200,000 B
  int*   off     = (int*)(ws + 200000);          // 200,004 B
  int*   cursor  = (int*)(ws + 400016);          // 200,000 B
  int*   eid     = (int*)(ws + 600016);          // 3,200,000 B (scan partials early)
  int*   csr_src = (int*)(ws + 3800016);         // 3,200,000 B
  int*   csr_dst = (int*)(ws + 7000016);         // 3,200,000 B
  float* e_sum   = (float*)(ws + 10200016);      // 12,800,000 B (f32)
  u16*   w1y     = (u16*)(ws + 23000016);        // 163,840 B
  u16*   w2y     = (u16*)(ws + 23163856);        // 32,768 B
  u16*   wn1t    = (u16*)(ws + 23196624);        // 98,304 B
  u16*   wn2t    = (u16*)(ws + 23294928);        // 65,536 B
  u16*   nfb     = (u16*)(ws + 23360464);        // 12,800,000 B  (end ~36.2 MB)

  hipMemsetAsync(hist, 0, 200000, stream);
  hipMemsetAsync(e_sum, 0, 12800000, stream);
  prep_weights<<<512, 256, 0, stream>>>(We1, We2, Wn1, Wn2, nf, dst,
                                        w1y, w2y, wn1t, wn2t, nfb, hist);
  scanA_kernel<<<NB_SCAN, 256, 0, stream>>>(hist, eid);
  scanB_kernel<<<1, 256, 0, stream>>>(eid, off);
  scanC_kernel<<<NB_SCAN, 256, 0, stream>>>(hist, eid, off, cursor);
  scatter_kernel<<<(N_EDGES + 255) / 256, 256, 0, stream>>>(src, dst, cursor, eid,
                                                            csr_src, csr_dst);

  edge_mlp<<<N_EDGES / 128, 256, 0, stream>>>(nfb, ef, eid, csr_src, csr_dst,
                                              w1y, be1, w2y, be2, e_sum, out_edge);
  node_kernel<<<(N_NODES + 63) / 64, 256, 0, stream>>>(nf, e_sum, hist,
                                                       wn1t, bn1, wn2t, bn2, hout);
}